// Round 11
// baseline (606.281 us; speedup 1.0000x reference)
//
#include <hip/hip_runtime.h>
#include <hip/hip_bf16.h>

#define T_SEQ 2048
#define CHUNK 16
#define NCHUNK 129           // 129 chunks x 16 steps = 2064 wave-steps >= 2051
#define NSCAN 16             // scan blocks (blockIdx 0..15)
#define NBLK  256            // total blocks = 256 CUs, 1 block/CU (LDS-forced)
#define NGW   1920           // GEMM waves = (256-16) blocks * 8 waves
#define L2E  1.44269504088896340736f
#define L2E2 2.88539008177792681472f
#define GX0_FLOATS (T_SEQ * 64 * 9)

typedef float vf2 __attribute__((ext_vector_type(2)));

// ---------------- cross-lane / math helpers ----------------
template<int CTRL>
__device__ __forceinline__ float dppmov(float v) {
    return __int_as_float(__builtin_amdgcn_update_dpp(
        0, __float_as_int(v), CTRL, 0xF, 0xF, true));
}
template<int CTRL>
__device__ __forceinline__ float dppadd(float v) { return v + dppmov<CTRL>(v); }
__device__ __forceinline__ float swzadd16(float v) {
    return v + __int_as_float(__builtin_amdgcn_ds_swizzle(__float_as_int(v), 0x401F));
}
__device__ __forceinline__ float frcp(float x) { return __builtin_amdgcn_rcpf(x); }
__device__ __forceinline__ float ex2(float x)  { return __builtin_amdgcn_exp2f(x); }
__device__ __forceinline__ vf2 pkfma(vf2 a, float b, vf2 c) {
    vf2 bb = { b, b };
    return __builtin_elementwise_fma(a, bb, c);   // -> v_pk_fma_f32
}

#define RING_BARRIER() asm volatile("s_waitcnt lgkmcnt(0)\ns_barrier" ::: "memory")

// ---------------------------------------------------------------------------
// Fused kernel, 256 blocks x 512 threads, ~96KB static LDS => 1 block/CU.
//   blocks 0..15 : GRU scan. Wave 0 = producer (LDS-only recurrence),
//                  wave 1 = consumer (all global traffic), waves 2..7 exit
//                  (HW decrements barrier count on wave exit).
//   blocks 16..255: persistent layer-0 projection, 8 waves each (1920 GEMM
//                  waves total -> enough TLP to stream x at ~3 TB/s),
//                  published per 1024-row chunk via release atomicAdd.
// gx0[row][g] = clamp((dot+b)*scale, +-50); scale=+log2e (r,z) / -2log2e (n).
// ---------------------------------------------------------------------------
__global__ __launch_bounds__(512) void fused_gru(
    const float* __restrict__ x,
    const float* __restrict__ hxs,
    const float* __restrict__ w_ih0, const float* __restrict__ w_hh0,
    const float* __restrict__ b_ih0, const float* __restrict__ b_hh0,
    const float* __restrict__ w_ih_rest, const float* __restrict__ w_hh_rest,
    const float* __restrict__ b_ih_rest, const float* __restrict__ b_hh_rest,
    float* __restrict__ out,             // [T*64*3 + 4*64*3]
    float* __restrict__ gx0,             // ws: [T*64*9]
    int*   __restrict__ cnt)             // ws: [128] chunk counters (memset 0)
{
    // 96KB static LDS: forces 1 block/CU (2 blocks would need 192KB > 160KB).
    __shared__ __align__(16) char lds_all[98304];
    const int lane = threadIdx.x & 63;

    if (blockIdx.x >= NSCAN) {
        // ================= persistent GEMM blocks (layer-0 proj) =================
        const int wid   = threadIdx.x >> 6;                       // 0..7
        const int gwave = ((int)blockIdx.x - NSCAN) * 8 + wid;    // 0..1919

        float4 wA[9], wB[9];
#pragma unroll
        for (int g = 0; g < 9; ++g) {
            const float s = (g < 6) ? L2E : -L2E2;
            float4 a = *(const float4*)&w_ih0[g * 512 + lane * 4];
            float4 b = *(const float4*)&w_ih0[g * 512 + 256 + lane * 4];
            wA[g] = make_float4(a.x * s, a.y * s, a.z * s, a.w * s);
            wB[g] = make_float4(b.x * s, b.y * s, b.z * s, b.w * s);
        }
        const float bval = (lane < 9) ? b_ih0[lane] * ((lane < 6) ? L2E : -L2E2) : 0.f;

#pragma unroll 1
        for (int grpi = gwave; grpi < 8192; grpi += NGW) {
            size_t row0 = (size_t)grpi * 16;
            const float4* xp = (const float4*)(x + row0 * 512);
            float4 xa = xp[lane];
            float4 xb = xp[64 + lane];

#pragma unroll 1
            for (int i = 0; i < 16; ++i) {
                float4 na = xa, nb = xb;
                if (i < 15) {
                    na = xp[(i + 1) * 128 + lane];
                    nb = xp[(i + 1) * 128 + 64 + lane];
                }
                float r[9];
#pragma unroll
                for (int g = 0; g < 9; ++g) {
                    float s = xa.x * wA[g].x;
                    s = fmaf(xa.y, wA[g].y, s);
                    s = fmaf(xa.z, wA[g].z, s);
                    s = fmaf(xa.w, wA[g].w, s);
                    s = fmaf(xb.x, wB[g].x, s);
                    s = fmaf(xb.y, wB[g].y, s);
                    s = fmaf(xb.z, wB[g].z, s);
                    s = fmaf(xb.w, wB[g].w, s);
                    s = dppadd<0xB1>(s);
                    s = dppadd<0x4E>(s);
                    s = dppadd<0x124>(s);
                    s = dppadd<0x128>(s);
                    s = swzadd16(s);
                    s += __shfl_xor(s, 32, 64);
                    r[g] = s;
                }
                float o = r[0];
#pragma unroll
                for (int g = 1; g < 9; ++g) o = (lane == g) ? r[g] : o;
                if (lane < 9) {
                    float v = fminf(fmaxf(o + bval, -50.f), 50.f);
                    __hip_atomic_store((unsigned int*)(gx0 + (row0 + i) * 9 + lane),
                                       __float_as_uint(v),
                                       __ATOMIC_RELAXED, __HIP_MEMORY_SCOPE_AGENT);
                }
                xa = na; xb = nb;
            }
            // publish: 64 groups per chunk
            if (lane == 0)
                __hip_atomic_fetch_add(&cnt[grpi >> 6], 1,
                                       __ATOMIC_RELEASE, __HIP_MEMORY_SCOPE_AGENT);
        }
        return;
    }

    // ============================ scan blocks ============================
    const int tid = threadIdx.x;
    if (tid >= 128) return;   // waves 2..7 exit (HW adjusts barrier count)

    float4 (*gxb)[CHUNK][64] = (float4 (*)[CHUNK][64])lds_all;            // 49152 B
    float  (*ring)[CHUNK][64] = (float (*)[CHUNK][64])(lds_all + 49152);  // 8192 B

    if (tid < 64) {
        // ---------------------------- producer ----------------------------
        const int grp = lane >> 4;
        const int r_  = lane & 15;
        const int l   = r_ >> 2;
        const int j   = r_ & 3;
        const bool jok = (j < 3);
        const bool is0 = (l == 0);
        const int  b   = blockIdx.x * 4 + grp;
        const int  row0 = jok ? j : 0;

        vf2 wi01[3], wh01[3], bh01;
        float wi2[3], wh2[3], bh2;
        {
            float wi[3][3], wh[3][3], bh[3];
            const float sc[3] = {L2E, L2E, -L2E2};
#pragma unroll
            for (int m = 0; m < 3; ++m) {
                const int row = m * 3 + row0;
                if (l == 0) {
                    bh[m] = b_hh0[row] * sc[m];
#pragma unroll
                    for (int k = 0; k < 3; ++k) { wi[m][k] = 0.f; wh[m][k] = w_hh0[row * 3 + k] * sc[m]; }
                } else {
                    float bb = b_hh_rest[(l - 1) * 9 + row];
                    if (m < 2) bb += b_ih_rest[(l - 1) * 9 + row];
                    bh[m] = bb * sc[m];
#pragma unroll
                    for (int k = 0; k < 3; ++k) {
                        wi[m][k] = w_ih_rest[((l - 1) * 9 + row) * 3 + k] * sc[m];
                        wh[m][k] = w_hh_rest[((l - 1) * 9 + row) * 3 + k] * sc[m];
                    }
                }
            }
#pragma unroll
            for (int k = 0; k < 3; ++k) {
                wi01[k] = (vf2){wi[0][k], wi[1][k]};
                wh01[k] = (vf2){wh[0][k], wh[1][k]};
                wi2[k] = wi[2][k]; wh2[k] = wh[2][k];
            }
            bh01 = (vf2){bh[0], bh[1]};
            bh2  = bh[2];
        }
        const float bi2 = is0 ? 0.f : b_ih_rest[(l - 1) * 9 + 6 + row0] * (-L2E2);

        // constant slots for lanes FILL never writes (l>0, or j==3)
        if (!(is0 && jok)) {
            const float4 cv = make_float4(0.f, 0.f, bi2, 0.f);
#pragma unroll
            for (int f = 0; f < 3; ++f)
                for (int st = 0; st < CHUNK; ++st)
                    gxb[f][st][lane] = cv;
        }
        float h = jok ? hxs[(l * 64 + b) * 3 + j] : 0.f;

        RING_BARRIER();   // consumer has prefilled bufs 0,1

        float gp[4][3];
#define PREF(SL, BUF, ST)                                                           \
        do { const float4* _r = &gxb[BUF][ST][lane];                                \
             gp[SL][0] = _r->x; gp[SL][1] = _r->y; gp[SL][2] = _r->z; } while (0)

#pragma unroll
        for (int k = 0; k < 4; ++k) PREF(k, 0, k);

        int bufc = 0;

#define GSTEP(P, MODE, TT)                                                          \
        do {                                                                        \
            float c0 = gp[(P) & 3][0], c1 = gp[(P) & 3][1], c2 = gp[(P) & 3][2];    \
            if ((P) < CHUNK - 4) PREF((P) & 3, bufc, (P) + 4);                      \
            else                 PREF((P) & 3, bufn, (P) - (CHUNK - 4));            \
            float hv0 = dppmov<0x00>(h);                                            \
            float hv1 = dppmov<0x55>(h);                                            \
            float hv2 = dppmov<0xAA>(h);                                            \
            float xv0 = dppmov<0x114>(hv0);                                         \
            float xv1 = dppmov<0x114>(hv1);                                         \
            float xv2 = dppmov<0x114>(hv2);                                         \
            vf2 t1 = pkfma(wh01[0], hv0, bh01);                                     \
            vf2 t2 = pkfma(wh01[1], hv1, (vf2){c0, c1});                            \
            t1 = pkfma(wh01[2], hv2, t1);                                           \
            t2 = pkfma(wi01[0], xv0, t2);                                           \
            t1 = pkfma(wi01[1], xv1, t1);                                           \
            t2 = pkfma(wi01[2], xv2, t2);                                           \
            vf2 arz = t1 + t2;                                                      \
            float ghn = fmaf(wh2[0], hv0, fmaf(wh2[1], hv1, fmaf(wh2[2], hv2, bh2))); \
            float gxn = fmaf(wi2[0], xv0, fmaf(wi2[1], xv1, fmaf(wi2[2], xv2, c2))); \
            float er = ex2(-arz.x);                                                 \
            float ez = ex2(-arz.y);                                                 \
            float rr = frcp(1.0f + er);                                             \
            float argn = fmaf(rr, ghn, gxn);                                        \
            float en = ex2(argn);                                                   \
            vf2 hmhp = (vf2){h, h} + (vf2){-ez, ez};                                \
            float N  = fmaf(en, hmhp.x, hmhp.y);                                    \
            float enp1 = en + 1.0f;                                                 \
            float D  = fmaf(enp1, ez, enp1);                                        \
            float hn = N * frcp(D);                                                 \
            if (MODE == 0)      h = ((TT) >= 0)    ? hn : h;                        \
            else if (MODE == 2) h = ((TT) < T_SEQ) ? hn : h;                        \
            else                h = hn;                                             \
            ring[CB][(P)][lane] = hn;                                               \
        } while (0)

        // ---- chunk 0: t>=0 guards on first 4 steps ----
        {
            const int bufn = 1; const int CB = 0;
#pragma unroll
            for (int p = 0; p < 4; ++p)  GSTEP(p, 0, p - l);
#pragma unroll
            for (int p = 4; p < 16; ++p) GSTEP(p, 1, 0);
            RING_BARRIER();
            bufc = 1;
        }
        // ---- chunks 1..127 ----
#pragma unroll 1
        for (int c = 1; c < 128; ++c) {
            const int bufn = (bufc == 2) ? 0 : bufc + 1;
            const int CB = c & 1;
#pragma unroll
            for (int p = 0; p < 16; ++p) GSTEP(p, 1, 0);
            RING_BARRIER();
            bufc = bufn;
        }
        // ---- chunk 128 tail: s = 2048..2051 ----
        {
            const int bufn = (bufc == 2) ? 0 : bufc + 1;
            const int CB = 0;   // 128 & 1 == 0
#pragma unroll
            for (int p = 0; p < 4; ++p) GSTEP(p, 2, 2048 + p - l);
            RING_BARRIER();
        }
#undef GSTEP
#undef PREF
        if (jok) out[(size_t)T_SEQ * 192 + (l * 64 + b) * 3 + j] = h;
    } else {
        // ---------------------------- consumer ----------------------------
        const int blk = blockIdx.x;
        float* gxs = (float*)gxb;

#define WAITCHUNK(TC)                                                               \
        do { while (__hip_atomic_load(&cnt[TC], __ATOMIC_ACQUIRE,                   \
                                      __HIP_MEMORY_SCOPE_AGENT) < 64)               \
                 __builtin_amdgcn_s_sleep(8); } while (0)

#define FILL(F, T0)                                                                 \
        do {                                                                        \
            _Pragma("unroll")                                                       \
            for (int k = 0; k < 9; ++k) {                                           \
                int i   = k * 64 + lane;                                            \
                int st  = i / 36;                                                   \
                int rem = i - st * 36;                                              \
                int m   = rem / 12;                                                 \
                int pos = rem - m * 12;                                             \
                int bl  = pos / 3;                                                  \
                int jj  = pos - bl * 3;                                             \
                unsigned int raw = __hip_atomic_load(                               \
                    (const unsigned int*)(gx0 + (size_t)((T0) + st) * 576           \
                                          + (blk * 4 + bl) * 9 + m * 3 + jj),       \
                    __ATOMIC_RELAXED, __HIP_MEMORY_SCOPE_AGENT);                    \
                gxs[(((F) * CHUNK + st) * 64 + bl * 16 + jj) * 4 + m]               \
                    = __uint_as_float(raw);                                         \
            }                                                                       \
        } while (0)

#define DRAIN(CC)                                                                   \
        do {                                                                        \
            _Pragma("unroll")                                                       \
            for (int k = 0; k < 3; ++k) {                                           \
                int i  = k * 64 + lane;                                             \
                int p  = i / 12;                                                    \
                int q  = i - p * 12;                                                \
                int g2 = q / 3;                                                     \
                int jj = q - g2 * 3;                                                \
                int t  = (CC) * CHUNK + p - 3;                                      \
                float val = ring[(CC) & 1][p][g2 * 16 + 12 + jj];                   \
                if (t >= 0 && t < T_SEQ)                                            \
                    out[(size_t)t * 192 + (blk * 4 + g2) * 3 + jj] = val;           \
            }                                                                       \
        } while (0)

        WAITCHUNK(0); FILL(0, 0);
        WAITCHUNK(1); FILL(1, CHUNK);
        RING_BARRIER();

#pragma unroll 1
        for (int c = 0; c < NCHUNK; ++c) {
            const int f = c + 2;
            if (f <= 127) {
                WAITCHUNK(f);
                switch (f % 3) {   // compile-time-constant LDS buffer index
                    case 0: FILL(0, f * CHUNK); break;
                    case 1: FILL(1, f * CHUNK); break;
                    default: FILL(2, f * CHUNK); break;
                }
            }
            if (c >= 1) DRAIN(c - 1);
            RING_BARRIER();
        }
        DRAIN(NCHUNK - 1);
#undef FILL
#undef DRAIN
#undef WAITCHUNK
    }
}

// ---------------------------------------------------------------------------
extern "C" void kernel_launch(void* const* d_in, const int* in_sizes, int n_in,
                              void* d_out, int out_size, void* d_ws, size_t ws_size,
                              hipStream_t stream) {
    const float* x         = (const float*)d_in[0];
    const float* hxs       = (const float*)d_in[1];
    const float* w_ih0     = (const float*)d_in[2];
    const float* w_hh0     = (const float*)d_in[3];
    const float* b_ih0     = (const float*)d_in[4];
    const float* b_hh0     = (const float*)d_in[5];
    const float* w_ih_rest = (const float*)d_in[6];
    const float* w_hh_rest = (const float*)d_in[7];
    const float* b_ih_rest = (const float*)d_in[8];
    const float* b_hh_rest = (const float*)d_in[9];
    float* out = (float*)d_out;
    float* gx0 = (float*)d_ws;                                   // 4.72 MB
    int*   cnt = (int*)((char*)d_ws + (size_t)GX0_FLOATS * 4);   // 128 ints

    hipMemsetAsync(cnt, 0, 128 * sizeof(int), stream);
    hipLaunchKernelGGL(fused_gru, dim3(NBLK), dim3(512), 0, stream,
                       x, hxs, w_ih0, w_hh0, b_ih0, b_hh0,
                       w_ih_rest, w_hh_rest, b_ih_rest, b_hh_rest,
                       out, gx0, cnt);
}

// Round 12
// 395.201 us; speedup vs baseline: 1.5341x; 1.5341x over previous
//
#include <hip/hip_runtime.h>
#include <hip/hip_bf16.h>

#define T_SEQ 2048
#define CHUNK 16
#define NCHUNK 129           // 129 chunks x 16 steps = 2064 wave-steps >= 2051
#define NSCAN 16             // scan blocks (blockIdx 0..15)
#define NBLK  256            // total blocks = 256 CUs, 1 block/CU (LDS-forced)
#define NGW   1920           // GEMM waves = (256-16) blocks * 8 waves
#define L2E  1.44269504088896340736f
#define L2E2 2.88539008177792681472f
#define GX0_FLOATS (T_SEQ * 64 * 9)

typedef float vf2 __attribute__((ext_vector_type(2)));

// ---------------- cross-lane / math helpers ----------------
template<int CTRL>
__device__ __forceinline__ float dppmov(float v) {
    return __int_as_float(__builtin_amdgcn_update_dpp(
        0, __float_as_int(v), CTRL, 0xF, 0xF, true));
}
template<int CTRL>
__device__ __forceinline__ float dppadd(float v) { return v + dppmov<CTRL>(v); }
__device__ __forceinline__ float swzadd16(float v) {
    return v + __int_as_float(__builtin_amdgcn_ds_swizzle(__float_as_int(v), 0x401F));
}
__device__ __forceinline__ float frcp(float x) { return __builtin_amdgcn_rcpf(x); }
__device__ __forceinline__ float ex2(float x)  { return __builtin_amdgcn_exp2f(x); }
__device__ __forceinline__ vf2 pkfma(vf2 a, float b, vf2 c) {
    vf2 bb = { b, b };
    return __builtin_elementwise_fma(a, bb, c);   // -> v_pk_fma_f32
}

#define RING_BARRIER() asm volatile("s_waitcnt lgkmcnt(0)\ns_barrier" ::: "memory")

// ---------------------------------------------------------------------------
// Fused kernel, 256 blocks x 512 threads, ~96KB static LDS => 1 block/CU.
//   blocks 0..15 : GRU scan. Wave 0 = producer (LDS-only recurrence),
//                  wave 1 = consumer (all global traffic), waves 2..7 exit.
//   blocks 16..255: persistent layer-0 projection, 8 waves each.
// Coherence: ALL cross-XCD data moves via agent-scope RELAXED atomics, which
// bypass L1/L2 and hit the MALL (coherence point) directly. No acquire
// buffer_inv / release buffer_wbl2 anywhere (those full-cache maintenance ops
// at ~us each were the R9-R11 700us poison). Ordering: producers s_waitcnt
// vmcnt(0) before the relaxed publish atomicAdd -> gx0 values are MALL-visible
// before the counter moves; consumer polls relaxed, then reads gx0 relaxed.
// gx0[row][g] = clamp((dot+b)*scale, +-50); scale=+log2e (r,z) / -2log2e (n).
// ---------------------------------------------------------------------------
__global__ __launch_bounds__(512) void fused_gru(
    const float* __restrict__ x,
    const float* __restrict__ hxs,
    const float* __restrict__ w_ih0, const float* __restrict__ w_hh0,
    const float* __restrict__ b_ih0, const float* __restrict__ b_hh0,
    const float* __restrict__ w_ih_rest, const float* __restrict__ w_hh_rest,
    const float* __restrict__ b_ih_rest, const float* __restrict__ b_hh_rest,
    float* __restrict__ out,             // [T*64*3 + 4*64*3]
    float* __restrict__ gx0,             // ws: [T*64*9]
    int*   __restrict__ cnt)             // ws: [128] chunk counters (memset 0)
{
    // 96KB static LDS: forces 1 block/CU (2 blocks would need 192KB > 160KB).
    __shared__ __align__(16) char lds_all[98304];
    const int lane = threadIdx.x & 63;

    if (blockIdx.x >= NSCAN) {
        // ================= persistent GEMM blocks (layer-0 proj) =================
        const int wid   = threadIdx.x >> 6;                       // 0..7
        const int gwave = ((int)blockIdx.x - NSCAN) * 8 + wid;    // 0..1919

        float4 wA[9], wB[9];
#pragma unroll
        for (int g = 0; g < 9; ++g) {
            const float s = (g < 6) ? L2E : -L2E2;
            float4 a = *(const float4*)&w_ih0[g * 512 + lane * 4];
            float4 b = *(const float4*)&w_ih0[g * 512 + 256 + lane * 4];
            wA[g] = make_float4(a.x * s, a.y * s, a.z * s, a.w * s);
            wB[g] = make_float4(b.x * s, b.y * s, b.z * s, b.w * s);
        }
        const float bval = (lane < 9) ? b_ih0[lane] * ((lane < 6) ? L2E : -L2E2) : 0.f;

#pragma unroll 1
        for (int grpi = gwave; grpi < 8192; grpi += NGW) {
            size_t row0 = (size_t)grpi * 16;
            const float4* xp = (const float4*)(x + row0 * 512);
            float4 xa = xp[lane];
            float4 xb = xp[64 + lane];

#pragma unroll 1
            for (int i = 0; i < 16; ++i) {
                float4 na = xa, nb = xb;
                if (i < 15) {
                    na = xp[(i + 1) * 128 + lane];
                    nb = xp[(i + 1) * 128 + 64 + lane];
                }
                float r[9];
#pragma unroll
                for (int g = 0; g < 9; ++g) {
                    float s = xa.x * wA[g].x;
                    s = fmaf(xa.y, wA[g].y, s);
                    s = fmaf(xa.z, wA[g].z, s);
                    s = fmaf(xa.w, wA[g].w, s);
                    s = fmaf(xb.x, wB[g].x, s);
                    s = fmaf(xb.y, wB[g].y, s);
                    s = fmaf(xb.z, wB[g].z, s);
                    s = fmaf(xb.w, wB[g].w, s);
                    s = dppadd<0xB1>(s);
                    s = dppadd<0x4E>(s);
                    s = dppadd<0x124>(s);
                    s = dppadd<0x128>(s);
                    s = swzadd16(s);
                    s += __shfl_xor(s, 32, 64);
                    r[g] = s;
                }
                float o = r[0];
#pragma unroll
                for (int g = 1; g < 9; ++g) o = (lane == g) ? r[g] : o;
                if (lane < 9) {
                    float v = fminf(fmaxf(o + bval, -50.f), 50.f);
                    __hip_atomic_store((unsigned int*)(gx0 + (row0 + i) * 9 + lane),
                                       __float_as_uint(v),
                                       __ATOMIC_RELAXED, __HIP_MEMORY_SCOPE_AGENT);
                }
                xa = na; xb = nb;
            }
            // publish: stores above are MALL-visible once vmcnt retires; then
            // a RELAXED atomicAdd (no buffer_wbl2) moves the counter.
            asm volatile("s_waitcnt vmcnt(0)" ::: "memory");
            if (lane == 0)
                __hip_atomic_fetch_add(&cnt[grpi >> 6], 1,
                                       __ATOMIC_RELAXED, __HIP_MEMORY_SCOPE_AGENT);
        }
        return;
    }

    // ============================ scan blocks ============================
    const int tid = threadIdx.x;
    if (tid >= 128) return;   // waves 2..7 exit (HW adjusts barrier count)

    float4 (*gxb)[CHUNK][64] = (float4 (*)[CHUNK][64])lds_all;            // 49152 B
    float  (*ring)[CHUNK][64] = (float (*)[CHUNK][64])(lds_all + 49152);  // 8192 B

    if (tid < 64) {
        // ---------------------------- producer ----------------------------
        const int grp = lane >> 4;
        const int r_  = lane & 15;
        const int l   = r_ >> 2;
        const int j   = r_ & 3;
        const bool jok = (j < 3);
        const bool is0 = (l == 0);
        const int  b   = blockIdx.x * 4 + grp;
        const int  row0 = jok ? j : 0;

        vf2 wi01[3], wh01[3], bh01;
        float wi2[3], wh2[3], bh2;
        {
            float wi[3][3], wh[3][3], bh[3];
            const float sc[3] = {L2E, L2E, -L2E2};
#pragma unroll
            for (int m = 0; m < 3; ++m) {
                const int row = m * 3 + row0;
                if (l == 0) {
                    bh[m] = b_hh0[row] * sc[m];
#pragma unroll
                    for (int k = 0; k < 3; ++k) { wi[m][k] = 0.f; wh[m][k] = w_hh0[row * 3 + k] * sc[m]; }
                } else {
                    float bb = b_hh_rest[(l - 1) * 9 + row];
                    if (m < 2) bb += b_ih_rest[(l - 1) * 9 + row];
                    bh[m] = bb * sc[m];
#pragma unroll
                    for (int k = 0; k < 3; ++k) {
                        wi[m][k] = w_ih_rest[((l - 1) * 9 + row) * 3 + k] * sc[m];
                        wh[m][k] = w_hh_rest[((l - 1) * 9 + row) * 3 + k] * sc[m];
                    }
                }
            }
#pragma unroll
            for (int k = 0; k < 3; ++k) {
                wi01[k] = (vf2){wi[0][k], wi[1][k]};
                wh01[k] = (vf2){wh[0][k], wh[1][k]};
                wi2[k] = wi[2][k]; wh2[k] = wh[2][k];
            }
            bh01 = (vf2){bh[0], bh[1]};
            bh2  = bh[2];
        }
        const float bi2 = is0 ? 0.f : b_ih_rest[(l - 1) * 9 + 6 + row0] * (-L2E2);

        // constant slots for lanes FILL never writes (l>0, or j==3)
        if (!(is0 && jok)) {
            const float4 cv = make_float4(0.f, 0.f, bi2, 0.f);
#pragma unroll
            for (int f = 0; f < 3; ++f)
                for (int st = 0; st < CHUNK; ++st)
                    gxb[f][st][lane] = cv;
        }
        float h = jok ? hxs[(l * 64 + b) * 3 + j] : 0.f;

        RING_BARRIER();   // consumer has prefilled bufs 0,1

        float gp[4][3];
#define PREF(SL, BUF, ST)                                                           \
        do { const float4* _r = &gxb[BUF][ST][lane];                                \
             gp[SL][0] = _r->x; gp[SL][1] = _r->y; gp[SL][2] = _r->z; } while (0)

#pragma unroll
        for (int k = 0; k < 4; ++k) PREF(k, 0, k);

        int bufc = 0;

#define GSTEP(P, MODE, TT)                                                          \
        do {                                                                        \
            float c0 = gp[(P) & 3][0], c1 = gp[(P) & 3][1], c2 = gp[(P) & 3][2];    \
            if ((P) < CHUNK - 4) PREF((P) & 3, bufc, (P) + 4);                      \
            else                 PREF((P) & 3, bufn, (P) - (CHUNK - 4));            \
            float hv0 = dppmov<0x00>(h);                                            \
            float hv1 = dppmov<0x55>(h);                                            \
            float hv2 = dppmov<0xAA>(h);                                            \
            float xv0 = dppmov<0x114>(hv0);                                         \
            float xv1 = dppmov<0x114>(hv1);                                         \
            float xv2 = dppmov<0x114>(hv2);                                         \
            vf2 t1 = pkfma(wh01[0], hv0, bh01);                                     \
            vf2 t2 = pkfma(wh01[1], hv1, (vf2){c0, c1});                            \
            t1 = pkfma(wh01[2], hv2, t1);                                           \
            t2 = pkfma(wi01[0], xv0, t2);                                           \
            t1 = pkfma(wi01[1], xv1, t1);                                           \
            t2 = pkfma(wi01[2], xv2, t2);                                           \
            vf2 arz = t1 + t2;                                                      \
            float ghn = fmaf(wh2[0], hv0, fmaf(wh2[1], hv1, fmaf(wh2[2], hv2, bh2))); \
            float gxn = fmaf(wi2[0], xv0, fmaf(wi2[1], xv1, fmaf(wi2[2], xv2, c2))); \
            float er = ex2(-arz.x);                                                 \
            float ez = ex2(-arz.y);                                                 \
            float rr = frcp(1.0f + er);                                             \
            float argn = fmaf(rr, ghn, gxn);                                        \
            float en = ex2(argn);                                                   \
            vf2 hmhp = (vf2){h, h} + (vf2){-ez, ez};                                \
            float N  = fmaf(en, hmhp.x, hmhp.y);                                    \
            float enp1 = en + 1.0f;                                                 \
            float D  = fmaf(enp1, ez, enp1);                                        \
            float hn = N * frcp(D);                                                 \
            if (MODE == 0)      h = ((TT) >= 0)    ? hn : h;                        \
            else if (MODE == 2) h = ((TT) < T_SEQ) ? hn : h;                        \
            else                h = hn;                                             \
            ring[CB][(P)][lane] = hn;                                               \
        } while (0)

        // ---- chunk 0: t>=0 guards on first 4 steps ----
        {
            const int bufn = 1; const int CB = 0;
#pragma unroll
            for (int p = 0; p < 4; ++p)  GSTEP(p, 0, p - l);
#pragma unroll
            for (int p = 4; p < 16; ++p) GSTEP(p, 1, 0);
            RING_BARRIER();
            bufc = 1;
        }
        // ---- chunks 1..127 ----
#pragma unroll 1
        for (int c = 1; c < 128; ++c) {
            const int bufn = (bufc == 2) ? 0 : bufc + 1;
            const int CB = c & 1;
#pragma unroll
            for (int p = 0; p < 16; ++p) GSTEP(p, 1, 0);
            RING_BARRIER();
            bufc = bufn;
        }
        // ---- chunk 128 tail: s = 2048..2051 ----
        {
            const int bufn = (bufc == 2) ? 0 : bufc + 1;
            const int CB = 0;   // 128 & 1 == 0
#pragma unroll
            for (int p = 0; p < 4; ++p) GSTEP(p, 2, 2048 + p - l);
            RING_BARRIER();
        }
#undef GSTEP
#undef PREF
        if (jok) out[(size_t)T_SEQ * 192 + (l * 64 + b) * 3 + j] = h;
    } else {
        // ---------------------------- consumer ----------------------------
        const int blk = blockIdx.x;
        float* gxs = (float*)gxb;

        // RELAXED poll: no buffer_inv. Freshness comes from relaxed atomic
        // loads in FILL (L1/L2-bypass -> MALL).
#define WAITCHUNK(TC)                                                               \
        do { while (__hip_atomic_load(&cnt[TC], __ATOMIC_RELAXED,                   \
                                      __HIP_MEMORY_SCOPE_AGENT) < 64)               \
                 __builtin_amdgcn_s_sleep(8); } while (0)

#define FILL(F, T0)                                                                 \
        do {                                                                        \
            _Pragma("unroll")                                                       \
            for (int k = 0; k < 9; ++k) {                                           \
                int i   = k * 64 + lane;                                            \
                int st  = i / 36;                                                   \
                int rem = i - st * 36;                                              \
                int m   = rem / 12;                                                 \
                int pos = rem - m * 12;                                             \
                int bl  = pos / 3;                                                  \
                int jj  = pos - bl * 3;                                             \
                unsigned int raw = __hip_atomic_load(                               \
                    (const unsigned int*)(gx0 + (size_t)((T0) + st) * 576           \
                                          + (blk * 4 + bl) * 9 + m * 3 + jj),       \
                    __ATOMIC_RELAXED, __HIP_MEMORY_SCOPE_AGENT);                    \
                gxs[(((F) * CHUNK + st) * 64 + bl * 16 + jj) * 4 + m]               \
                    = __uint_as_float(raw);                                         \
            }                                                                       \
        } while (0)

#define DRAIN(CC)                                                                   \
        do {                                                                        \
            _Pragma("unroll")                                                       \
            for (int k = 0; k < 3; ++k) {                                           \
                int i  = k * 64 + lane;                                             \
                int p  = i / 12;                                                    \
                int q  = i - p * 12;                                                \
                int g2 = q / 3;                                                     \
                int jj = q - g2 * 3;                                                \
                int t  = (CC) * CHUNK + p - 3;                                      \
                float val = ring[(CC) & 1][p][g2 * 16 + 12 + jj];                   \
                if (t >= 0 && t < T_SEQ)                                            \
                    out[(size_t)t * 192 + (blk * 4 + g2) * 3 + jj] = val;           \
            }                                                                       \
        } while (0)

        WAITCHUNK(0); FILL(0, 0);
        WAITCHUNK(1); FILL(1, CHUNK);
        RING_BARRIER();

#pragma unroll 1
        for (int c = 0; c < NCHUNK; ++c) {
            const int f = c + 2;
            if (f <= 127) {
                WAITCHUNK(f);
                switch (f % 3) {   // compile-time-constant LDS buffer index
                    case 0: FILL(0, f * CHUNK); break;
                    case 1: FILL(1, f * CHUNK); break;
                    default: FILL(2, f * CHUNK); break;
                }
            }
            if (c >= 1) DRAIN(c - 1);
            RING_BARRIER();
        }
        DRAIN(NCHUNK - 1);
#undef FILL
#undef DRAIN
#undef WAITCHUNK
    }
}

// ---------------------------------------------------------------------------
extern "C" void kernel_launch(void* const* d_in, const int* in_sizes, int n_in,
                              void* d_out, int out_size, void* d_ws, size_t ws_size,
                              hipStream_t stream) {
    const float* x         = (const float*)d_in[0];
    const float* hxs       = (const float*)d_in[1];
    const float* w_ih0     = (const float*)d_in[2];
    const float* w_hh0     = (const float*)d_in[3];
    const float* b_ih0     = (const float*)d_in[4];
    const float* b_hh0     = (const float*)d_in[5];
    const float* w_ih_rest = (const float*)d_in[6];
    const float* w_hh_rest = (const float*)d_in[7];
    const float* b_ih_rest = (const float*)d_in[8];
    const float* b_hh_rest = (const float*)d_in[9];
    float* out = (float*)d_out;
    float* gx0 = (float*)d_ws;                                   // 4.72 MB
    int*   cnt = (int*)((char*)d_ws + (size_t)GX0_FLOATS * 4);   // 128 ints

    hipMemsetAsync(cnt, 0, 128 * sizeof(int), stream);
    hipLaunchKernelGGL(fused_gru, dim3(NBLK), dim3(512), 0, stream,
                       x, hxs, w_ih0, w_hh0, b_ih0, b_hh0,
                       w_ih_rest, w_hh_rest, b_ih_rest, b_hh_rest,
                       out, gx0, cnt);
}

// Round 14
// 217.708 us; speedup vs baseline: 2.7848x; 1.8153x over previous
//
#include <hip/hip_runtime.h>
#include <hip/hip_bf16.h>

#define T_SEQ 2048
#define CHUNK 16
#define NCHUNK 129           // 129 chunks x 16 steps = 2064 wave-steps >= 2051
#define L2E  1.44269504088896340736f
#define L2E2 2.88539008177792681472f

typedef float vf2 __attribute__((ext_vector_type(2)));

// ---------------- cross-lane / math helpers ----------------
template<int CTRL>
__device__ __forceinline__ float dppmov(float v) {
    return __int_as_float(__builtin_amdgcn_update_dpp(
        0, __float_as_int(v), CTRL, 0xF, 0xF, true));
}
template<int CTRL>
__device__ __forceinline__ float dppadd(float v) { return v + dppmov<CTRL>(v); }
__device__ __forceinline__ float swzadd16(float v) {
    return v + __int_as_float(__builtin_amdgcn_ds_swizzle(__float_as_int(v), 0x401F));
}
__device__ __forceinline__ float frcp(float x) { return __builtin_amdgcn_rcpf(x); }
__device__ __forceinline__ float ex2(float x)  { return __builtin_amdgcn_exp2f(x); }
__device__ __forceinline__ vf2 pkfma(vf2 a, float b, vf2 c) {
    vf2 bb = { b, b };
    return __builtin_elementwise_fma(a, bb, c);   // -> v_pk_fma_f32
}

#define RING_BARRIER() asm volatile("s_waitcnt lgkmcnt(0)\ns_barrier" ::: "memory")

// ---------------------------------------------------------------------------
// Kernel 1 (HBM roofline, ~45us): gx0[row][g] = clamp((dot+b)*scale, +-50)
// scale = +log2e for r,z rows (g<6); -2*log2e for n rows (g>=6), so the scan
// uses v_exp_f32 (exp2) directly. Clamp keeps the fused update finite.
// ---------------------------------------------------------------------------
__global__ __launch_bounds__(256) void gx0_kernel(
    const float* __restrict__ x, const float* __restrict__ w,
    const float* __restrict__ bias, float* __restrict__ gx0)
{
    const int lane = threadIdx.x & 63;
    const int gw   = (blockIdx.x * 256 + threadIdx.x) >> 6;

    float4 wA[9], wB[9];
#pragma unroll
    for (int g = 0; g < 9; ++g) {
        const float s = (g < 6) ? L2E : -L2E2;
        float4 a = *(const float4*)&w[g * 512 + lane * 4];
        float4 b = *(const float4*)&w[g * 512 + 256 + lane * 4];
        wA[g] = make_float4(a.x * s, a.y * s, a.z * s, a.w * s);
        wB[g] = make_float4(b.x * s, b.y * s, b.z * s, b.w * s);
    }
    const float bval = (lane < 9) ? bias[lane] * ((lane < 6) ? L2E : -L2E2) : 0.f;

    size_t row0 = (size_t)gw * 16;
    const float4* xp = (const float4*)(x + row0 * 512);
    float4 xa = xp[lane];
    float4 xb = xp[64 + lane];

#pragma unroll 1
    for (int i = 0; i < 16; ++i) {
        float4 na = xa, nb = xb;
        if (i < 15) {
            na = xp[(i + 1) * 128 + lane];
            nb = xp[(i + 1) * 128 + 64 + lane];
        }
        float r[9];
#pragma unroll
        for (int g = 0; g < 9; ++g) {
            float s = xa.x * wA[g].x;
            s = fmaf(xa.y, wA[g].y, s);
            s = fmaf(xa.z, wA[g].z, s);
            s = fmaf(xa.w, wA[g].w, s);
            s = fmaf(xb.x, wB[g].x, s);
            s = fmaf(xb.y, wB[g].y, s);
            s = fmaf(xb.z, wB[g].z, s);
            s = fmaf(xb.w, wB[g].w, s);
            s = dppadd<0xB1>(s);
            s = dppadd<0x4E>(s);
            s = dppadd<0x124>(s);
            s = dppadd<0x128>(s);
            s = swzadd16(s);
            s += __shfl_xor(s, 32, 64);
            r[g] = s;
        }
        float o = r[0];
#pragma unroll
        for (int g = 1; g < 9; ++g) o = (lane == g) ? r[g] : o;
        if (lane < 9) gx0[(row0 + i) * 9 + lane] = fminf(fmaxf(o + bval, -50.f), 50.f);
        xa = na; xb = nb;
    }
}

// ---------------------------------------------------------------------------
// Kernel 2: producer/consumer GRU scan (R6 structure — the proven best).
// Producer wave: LDS-only recurrence with fused single-division update
//   ez=e^-az, en=e^-2an: h' = (en(h-ez)+(h+ez)) / ((1+en)(1+ez)).
// Consumer wave: ALL global traffic (gx staging + out drain). Same-XCD LDS
// handshake with lgkmcnt-only barriers (producer loads stay in flight).
// This split exists because ANY global op in the recurrence wave costs
// ~3x its issue slots (R3/R4/R8 measured); cross-kernel XCD coherence games
// are unsound under the harness poison protocol (R13).
// ---------------------------------------------------------------------------
__global__ __launch_bounds__(128) void gru_scan(
    const float* __restrict__ gx0,        // [T*64*9] pre-scaled + clamped
    const float* __restrict__ hxs,
    const float* __restrict__ w_hh0, const float* __restrict__ b_hh0,
    const float* __restrict__ w_ih_rest, const float* __restrict__ w_hh_rest,
    const float* __restrict__ b_ih_rest, const float* __restrict__ b_hh_rest,
    float* __restrict__ out)              // [T*64*3 + 4*64*3]
{
    __shared__ float4 gxb[3][CHUNK][64];   // 48 KB
    __shared__ float  ring[2][CHUNK][64];  // 8 KB
    const int tid  = threadIdx.x;
    const int lane = tid & 63;

    if (tid < 64) {
        // ============================ producer ============================
        __builtin_amdgcn_s_setprio(1);     // latency-critical wave: prefer it
        const int grp = lane >> 4;
        const int r_  = lane & 15;
        const int l   = r_ >> 2;
        const int j   = r_ & 3;
        const bool jok = (j < 3);
        const bool is0 = (l == 0);
        const int  b   = blockIdx.x * 4 + grp;
        const int  row0 = jok ? j : 0;

        // packed r/z rows (scale +L2E, b_ih folded into bh) ; n row scale -L2E2
        vf2 wi01[3], wh01[3], bh01;
        float wi2[3], wh2[3], bh2;
        {
            float wi[3][3], wh[3][3], bh[3];
            const float sc[3] = {L2E, L2E, -L2E2};
#pragma unroll
            for (int m = 0; m < 3; ++m) {
                const int row = m * 3 + row0;
                if (l == 0) {
                    bh[m] = b_hh0[row] * sc[m];
#pragma unroll
                    for (int k = 0; k < 3; ++k) { wi[m][k] = 0.f; wh[m][k] = w_hh0[row * 3 + k] * sc[m]; }
                } else {
                    float bb = b_hh_rest[(l - 1) * 9 + row];
                    if (m < 2) bb += b_ih_rest[(l - 1) * 9 + row];
                    bh[m] = bb * sc[m];
#pragma unroll
                    for (int k = 0; k < 3; ++k) {
                        wi[m][k] = w_ih_rest[((l - 1) * 9 + row) * 3 + k] * sc[m];
                        wh[m][k] = w_hh_rest[((l - 1) * 9 + row) * 3 + k] * sc[m];
                    }
                }
            }
#pragma unroll
            for (int k = 0; k < 3; ++k) {
                wi01[k] = (vf2){wi[0][k], wi[1][k]};
                wh01[k] = (vf2){wh[0][k], wh[1][k]};
                wi2[k] = wi[2][k]; wh2[k] = wh[2][k];
            }
            bh01 = (vf2){bh[0], bh[1]};
            bh2  = bh[2];
        }
        const float bi2 = is0 ? 0.f : b_ih_rest[(l - 1) * 9 + 6 + row0] * (-L2E2);

        // constant gx slots for lanes the consumer never writes (l>0, or j==3)
        if (!(is0 && jok)) {
            const float4 cv = make_float4(0.f, 0.f, bi2, 0.f);
#pragma unroll
            for (int f = 0; f < 3; ++f)
                for (int st = 0; st < CHUNK; ++st)
                    gxb[f][st][lane] = cv;
        }
        float h = jok ? hxs[(l * 64 + b) * 3 + j] : 0.f;

        RING_BARRIER();   // consumer has prefilled bufs 0,1

        float gp[4][3];
#define PREF(SL, BUF, ST)                                                           \
        do { const float4* _r = &gxb[BUF][ST][lane];                                \
             gp[SL][0] = _r->x; gp[SL][1] = _r->y; gp[SL][2] = _r->z; } while (0)

#pragma unroll
        for (int k = 0; k < 4; ++k) PREF(k, 0, k);

        int bufc = 0;

#define GSTEP(P, MODE, TT)                                                          \
        do {                                                                        \
            float c0 = gp[(P) & 3][0], c1 = gp[(P) & 3][1], c2 = gp[(P) & 3][2];    \
            if ((P) < CHUNK - 4) PREF((P) & 3, bufc, (P) + 4);                      \
            else                 PREF((P) & 3, bufn, (P) - (CHUNK - 4));            \
            float hv0 = dppmov<0x00>(h);                                            \
            float hv1 = dppmov<0x55>(h);                                            \
            float hv2 = dppmov<0xAA>(h);                                            \
            float xv0 = dppmov<0x114>(hv0);                                         \
            float xv1 = dppmov<0x114>(hv1);                                         \
            float xv2 = dppmov<0x114>(hv2);                                         \
            vf2 t1 = pkfma(wh01[0], hv0, bh01);                                     \
            vf2 t2 = pkfma(wh01[1], hv1, (vf2){c0, c1});                            \
            t1 = pkfma(wh01[2], hv2, t1);                                           \
            t2 = pkfma(wi01[0], xv0, t2);                                           \
            t1 = pkfma(wi01[1], xv1, t1);                                           \
            t2 = pkfma(wi01[2], xv2, t2);                                           \
            vf2 arz = t1 + t2;                                                      \
            float ghn = fmaf(wh2[0], hv0, fmaf(wh2[1], hv1, fmaf(wh2[2], hv2, bh2))); \
            float gxn = fmaf(wi2[0], xv0, fmaf(wi2[1], xv1, fmaf(wi2[2], xv2, c2))); \
            float er = ex2(-arz.x);                                                 \
            float ez = ex2(-arz.y);                                                 \
            float rr = frcp(1.0f + er);                                             \
            float argn = fmaf(rr, ghn, gxn);                                        \
            float en = ex2(argn);                                                   \
            float hm = h - ez;                                                      \
            float hp = h + ez;                                                      \
            float N  = fmaf(en, hm, hp);                                            \
            float enp1 = en + 1.0f;                                                 \
            float D  = fmaf(enp1, ez, enp1);                                        \
            float hn = N * frcp(D);                                                 \
            if (MODE == 0)      h = ((TT) >= 0)    ? hn : h;                        \
            else if (MODE == 2) h = ((TT) < T_SEQ) ? hn : h;                        \
            else                h = hn;                                             \
            ring[CB][(P)][lane] = hn;                                               \
        } while (0)

        // ---- chunk 0: steps 0..15, t>=0 guard on first 4 ----
        {
            const int bufn = 1; const int CB = 0;
#pragma unroll
            for (int p = 0; p < 4; ++p)  GSTEP(p, 0, p - l);
#pragma unroll
            for (int p = 4; p < 16; ++p) GSTEP(p, 1, 0);
            RING_BARRIER();
            bufc = 1;
        }
        // ---- chunks 1..127: no guards ----
#pragma unroll 1
        for (int c = 1; c < 128; ++c) {
            const int bufn = (bufc == 2) ? 0 : bufc + 1;
            const int CB = c & 1;
#pragma unroll
            for (int p = 0; p < 16; ++p) GSTEP(p, 1, 0);
            RING_BARRIER();
            bufc = bufn;
        }
        // ---- chunk 128 tail: s = 2048..2051, t<T guard ----
        {
            const int bufn = (bufc == 2) ? 0 : bufc + 1;
            const int CB = 0;   // 128 & 1 == 0
#pragma unroll
            for (int p = 0; p < 4; ++p) GSTEP(p, 2, 2048 + p - l);
            RING_BARRIER();
        }
#undef GSTEP
#undef PREF
        // final hidden states (once, off critical path)
        if (jok) out[(size_t)T_SEQ * 192 + (l * 64 + b) * 3 + j] = h;
    } else {
        // ============================ consumer ============================
        const int blk = blockIdx.x;
        float* gxs = (float*)gxb;

#define FILL(F, T0)                                                                 \
        do {                                                                        \
            _Pragma("unroll")                                                       \
            for (int k = 0; k < 9; ++k) {                                           \
                int i   = k * 64 + lane;                                            \
                int st  = i / 36;                                                   \
                int rem = i - st * 36;                                              \
                int m   = rem / 12;                                                 \
                int pos = rem - m * 12;                                             \
                int bl  = pos / 3;                                                  \
                int jj  = pos - bl * 3;                                             \
                float val = gx0[(size_t)((T0) + st) * 576 + (blk * 4 + bl) * 9 + m * 3 + jj]; \
                gxs[(((F) * CHUNK + st) * 64 + bl * 16 + jj) * 4 + m] = val;        \
            }                                                                       \
        } while (0)

#define DRAIN(CC)                                                                   \
        do {                                                                        \
            _Pragma("unroll")                                                       \
            for (int k = 0; k < 3; ++k) {                                           \
                int i  = k * 64 + lane;                                             \
                int p  = i / 12;                                                    \
                int q  = i - p * 12;                                                \
                int g2 = q / 3;                                                     \
                int jj = q - g2 * 3;                                                \
                int t  = (CC) * CHUNK + p - 3;                                      \
                float val = ring[(CC) & 1][p][g2 * 16 + 12 + jj];                   \
                if (t >= 0 && t < T_SEQ)                                            \
                    out[(size_t)t * 192 + (blk * 4 + g2) * 3 + jj] = val;           \
            }                                                                       \
        } while (0)

        FILL(0, 0);
        FILL(1, CHUNK);
        RING_BARRIER();

#pragma unroll 1
        for (int c = 0; c < NCHUNK; ++c) {
            const int f = c + 2;
            if (f <= 127) {
                switch (f % 3) {   // compile-time-constant LDS buffer index
                    case 0: FILL(0, f * CHUNK); break;
                    case 1: FILL(1, f * CHUNK); break;
                    default: FILL(2, f * CHUNK); break;
                }
            }
            if (c >= 1) DRAIN(c - 1);
            RING_BARRIER();
        }
        DRAIN(NCHUNK - 1);
#undef FILL
#undef DRAIN
    }
}

// ---------------------------------------------------------------------------
extern "C" void kernel_launch(void* const* d_in, const int* in_sizes, int n_in,
                              void* d_out, int out_size, void* d_ws, size_t ws_size,
                              hipStream_t stream) {
    const float* x         = (const float*)d_in[0];
    const float* hxs       = (const float*)d_in[1];
    const float* w_ih0     = (const float*)d_in[2];
    const float* w_hh0     = (const float*)d_in[3];
    const float* b_ih0     = (const float*)d_in[4];
    const float* b_hh0     = (const float*)d_in[5];
    const float* w_ih_rest = (const float*)d_in[6];
    const float* w_hh_rest = (const float*)d_in[7];
    const float* b_ih_rest = (const float*)d_in[8];
    const float* b_hh_rest = (const float*)d_in[9];
    float* out = (float*)d_out;
    float* gx0 = (float*)d_ws;   // T*64*9*4 = 4.72 MB

    hipLaunchKernelGGL(gx0_kernel, dim3(2048), dim3(256), 0, stream,
                       x, w_ih0, b_ih0, gx0);
    hipLaunchKernelGGL(gru_scan, dim3(16), dim3(128), 0, stream,
                       gx0, hxs, w_hh0, b_hh0, w_ih_rest, w_hh_rest,
                       b_ih_rest, b_hh_rest, out);
}